// Round 2
// baseline (1938.904 us; speedup 1.0000x reference)
//
#include <hip/hip_runtime.h>

#define BATCH 16
#define SEQ 8192
#define CH 32
#define NB 24

__device__ __forceinline__ float rcp_fast(float x) { return __builtin_amdgcn_rcpf(x); }

__device__ __forceinline__ float fast_tanh(float x) {
    float ax = fabsf(x);
    float e = __expf(-2.0f * ax);
    float t = (1.0f - e) * rcp_fast(1.0f + e);
    return copysignf(t, x);
}

__device__ __forceinline__ float fast_sigmoid(float x) {
    return rcp_fast(1.0f + __expf(-x));
}

// ---------------- transpose W1 (NB,32,32) -> W1t (NB,32c,32o) so the skip
// column access in k_block is a contiguous scalar load
__global__ __launch_bounds__(256) void k_prep(const float* __restrict__ W1,
                                              float* __restrict__ W1t) {
    int idx = blockIdx.x * 256 + threadIdx.x;      // 0 .. NB*1024-1
    int i = idx >> 10, rem = idx & 1023;
    int o = rem >> 5, c = rem & 31;
    W1t[i * 1024 + c * 32 + o] = W1[i * 1024 + o * 32 + c];
}

// ---------------- initial causal conv (1 -> 32 ch, K=2, dil=1); zero pooled
__global__ __launch_bounds__(256) void k_init(const float* __restrict__ x,
                                              const float* __restrict__ W0,
                                              const float* __restrict__ b0,
                                              float* __restrict__ h,
                                              float* __restrict__ pooled) {
    int idx = blockIdx.x * 256 + threadIdx.x;      // 0 .. BATCH*SEQ-1
    int b = idx >> 13, t = idx & (SEQ - 1);
    float xt = x[b * SEQ + t];
    float xm = (t > 0) ? x[b * SEQ + t - 1] : 0.0f;
#pragma unroll
    for (int c = 0; c < CH; ++c)
        h[(b * CH + c) * SEQ + t] = W0[c * 2 + 0] * xm + W0[c * 2 + 1] * xt + b0[c];
    if (idx < BATCH * CH * 4) pooled[idx] = 0.0f;  // atomic-max target
}

// ---------------- one WaveNet block: dilated conv(32->64) -> gate -> 1x1 skip
// -> h_out = h_in + skip.  (skip_sum recovered later as h_final - h_0.)
__global__ __launch_bounds__(256) void k_block(const float* __restrict__ hin,
                                               float* __restrict__ hout,
                                               const float* __restrict__ Wd,   // (64,32,2)
                                               const float* __restrict__ bd,   // (64)
                                               const float* __restrict__ W1t,  // (32c,32o)
                                               const float* __restrict__ b1,   // (32)
                                               int dil) {
    int idx = blockIdx.x * 256 + threadIdx.x;
    int b = idx >> 13, t = idx & (SEQ - 1);
    const float* hb = hin + b * CH * SEQ + t;

    float ht[CH], htd[CH];
    bool ok = (t >= dil);
#pragma unroll
    for (int c = 0; c < CH; ++c) {
        ht[c] = hb[c * SEQ];
        htd[c] = ok ? hb[c * SEQ - dil] : 0.0f;
    }

    float skip[CH];
#pragma unroll
    for (int o = 0; o < CH; ++o) skip[o] = b1[o];

    float gated_prev = 0.0f;
#pragma unroll 1
    for (int c = 0; c < CH; ++c) {                  // gate channel (rolled)
        const float* wf_ = Wd + c * (CH * 2);
        const float* wg_ = Wd + (c + CH) * (CH * 2);
        float f = bd[c], g = bd[c + CH];
        float f1 = 0.0f, g1 = 0.0f;
#pragma unroll
        for (int cc = 0; cc < CH; cc += 2) {
            f  += wf_[cc * 2 + 0] * htd[cc]     + wf_[cc * 2 + 1] * ht[cc];
            f1 += wf_[cc * 2 + 2] * htd[cc + 1] + wf_[cc * 2 + 3] * ht[cc + 1];
            g  += wg_[cc * 2 + 0] * htd[cc]     + wg_[cc * 2 + 1] * ht[cc];
            g1 += wg_[cc * 2 + 2] * htd[cc + 1] + wg_[cc * 2 + 3] * ht[cc + 1];
        }
        // software-pipelined skip update for c-1: independent FMAs that fill
        // the exp/rcp dependency tail of gated_prev's successor below
        if (c > 0) {
            const float* w1p = W1t + (c - 1) * CH;
#pragma unroll
            for (int o = 0; o < CH; ++o) skip[o] += w1p[o] * gated_prev;
        }
        gated_prev = fast_tanh(f + f1) * fast_sigmoid(g + g1);
    }
    {
        const float* w1l = W1t + (CH - 1) * CH;
#pragma unroll
        for (int o = 0; o < CH; ++o) skip[o] += w1l[o] * gated_prev;
    }

    float* ho = hout + b * CH * SEQ + t;
#pragma unroll
    for (int o = 0; o < CH; ++o) ho[o * SEQ] = ht[o] + skip[o];
}

// ---------------- relu(h_fin - h0) -> Wf GEMM -> relu -> chunk max -> atomicMax
__global__ __launch_bounds__(256) void k_final1(const float* __restrict__ hfin,
                                                const float* __restrict__ h0,
                                                const float* __restrict__ Wf,  // (32,32)
                                                const float* __restrict__ bf,
                                                float* __restrict__ pooled) {  // (B,32*4)
    int blk = blockIdx.x;                  // 512 blocks: b(4b) | q(2b) | s(3b)
    int b = blk >> 5;
    int q = (blk >> 3) & 3;
    int s = blk & 7;
    int t = q * (SEQ / 4) + s * 256 + threadIdx.x;
    const float* hf = hfin + b * CH * SEQ + t;
    const float* hz = h0 + b * CH * SEQ + t;

    float r[CH];
#pragma unroll
    for (int c = 0; c < CH; ++c) r[c] = fmaxf(hf[c * SEQ] - hz[c * SEQ], 0.0f);

    float y[CH];
#pragma unroll 1
    for (int o = 0; o < CH; ++o) {
        const float* w = Wf + o * CH;
        float a0 = bf[o], a1 = 0.0f, a2 = 0.0f, a3 = 0.0f;
#pragma unroll
        for (int c = 0; c < CH; c += 4) {
            a0 += w[c + 0] * r[c + 0];
            a1 += w[c + 1] * r[c + 1];
            a2 += w[c + 2] * r[c + 2];
            a3 += w[c + 3] * r[c + 3];
        }
        y[o] = fmaxf((a0 + a1) + (a2 + a3), 0.0f);
    }

    // 64-lane butterfly max per channel
#pragma unroll
    for (int o = 0; o < CH; ++o) {
#pragma unroll
        for (int off = 32; off >= 1; off >>= 1)
            y[o] = fmaxf(y[o], __shfl_xor(y[o], off));
    }

    __shared__ float red[4 * CH];
    int wave = threadIdx.x >> 6, lane = threadIdx.x & 63;
    if (lane == 0) {
#pragma unroll
        for (int o = 0; o < CH; ++o) red[wave * CH + o] = y[o];
    }
    __syncthreads();
    if (threadIdx.x < CH) {
        float m = fmaxf(fmaxf(red[threadIdx.x], red[CH + threadIdx.x]),
                        fmaxf(red[2 * CH + threadIdx.x], red[3 * CH + threadIdx.x]));
        // values are post-relu (>= 0): uint compare == float compare
        atomicMax((unsigned int*)&pooled[b * (CH * 4) + threadIdx.x * 4 + q],
                  __float_as_uint(m));
    }
}

// ---------------- final MLP: (B,128) -> relu FC 64 -> FC 10
__global__ __launch_bounds__(1024) void k_final2(const float* __restrict__ pooled,
                                                 const float* __restrict__ fW1, // (64,128)
                                                 const float* __restrict__ fb1,
                                                 const float* __restrict__ fW2, // (10,64)
                                                 const float* __restrict__ fb2,
                                                 float* __restrict__ out) {
    __shared__ float y1[BATCH * 64];
    int tid = threadIdx.x;
    int b = tid >> 6, o = tid & 63;
    float acc = fb1[o];
#pragma unroll
    for (int j = 0; j < 128; ++j) acc += fW1[o * 128 + j] * pooled[b * 128 + j];
    y1[b * 64 + o] = fmaxf(acc, 0.0f);
    __syncthreads();
    if (tid < BATCH * 10) {
        int bb = tid / 10, o2 = tid % 10;
        float a2 = fb2[o2];
#pragma unroll
        for (int j = 0; j < 64; ++j) a2 += fW2[o2 * 64 + j] * y1[bb * 64 + j];
        out[bb * 10 + o2] = a2;
    }
}

extern "C" void kernel_launch(void* const* d_in, const int* in_sizes, int n_in,
                              void* d_out, int out_size, void* d_ws, size_t ws_size,
                              hipStream_t stream) {
    const float* x   = (const float*)d_in[0];
    const float* W0  = (const float*)d_in[1];
    const float* b0  = (const float*)d_in[2];
    const float* Wd  = (const float*)d_in[3];
    const float* bd  = (const float*)d_in[4];
    const float* W1  = (const float*)d_in[5];
    const float* b1  = (const float*)d_in[6];
    const float* Wf  = (const float*)d_in[7];
    const float* bf  = (const float*)d_in[8];
    const float* fW1 = (const float*)d_in[9];
    const float* fb1 = (const float*)d_in[10];
    const float* fW2 = (const float*)d_in[11];
    const float* fb2 = (const float*)d_in[12];
    float* out = (float*)d_out;

    const size_t HS = (size_t)BATCH * CH * SEQ;    // 4 M floats = 16 MB
    float* h0     = (float*)d_ws;
    float* bufA   = h0 + HS;
    float* bufB   = bufA + HS;
    float* pooled = bufB + HS;                     // 2048 floats
    float* W1t    = pooled + BATCH * CH * 4;       // 24576 floats

    const int grid = BATCH * SEQ / 256;            // 512

    k_prep<<<NB * 4, 256, 0, stream>>>(W1, W1t);
    k_init<<<grid, 256, 0, stream>>>(x, W0, b0, h0, pooled);

    const float* hin = h0;
    for (int i = 0; i < NB; ++i) {
        float* hout = (i & 1) ? bufB : bufA;
        int dil = 1 << (i & 7);
        k_block<<<grid, 256, 0, stream>>>(hin, hout,
                                          Wd + (size_t)i * 64 * CH * 2,
                                          bd + (size_t)i * 64,
                                          W1t + (size_t)i * CH * CH,
                                          b1 + (size_t)i * CH, dil);
        hin = hout;
    }
    // 24 blocks: last output is bufB

    k_final1<<<512, 256, 0, stream>>>(bufB, h0, Wf, bf, pooled);
    k_final2<<<1, 1024, 0, stream>>>(pooled, fW1, fb1, fW2, fb2, out);
}

// Round 3
// 444.936 us; speedup vs baseline: 4.3577x; 4.3577x over previous
//
#include <hip/hip_runtime.h>

#define BATCH 16
#define SEQ 8192
#define CH 32
#define NB 24

typedef __attribute__((ext_vector_type(8))) short short8;
typedef __attribute__((ext_vector_type(4))) short short4v;
typedef __attribute__((ext_vector_type(4))) float f32x4;

__device__ __forceinline__ unsigned short f2bf(float x) {
    unsigned int u = __float_as_uint(x);
    unsigned int r = (u + 0x7FFFu + ((u >> 16) & 1u)) >> 16;
    return (unsigned short)r;
}
__device__ __forceinline__ float bf2f(unsigned short h) {
    return __uint_as_float(((unsigned int)h) << 16);
}

__device__ __forceinline__ float rcp_fast(float x) { return __builtin_amdgcn_rcpf(x); }

__device__ __forceinline__ float fast_tanh(float x) {
    float ax = fabsf(x);
    float e = __expf(-2.0f * ax);
    float t = (1.0f - e) * rcp_fast(1.0f + e);
    return copysignf(t, x);
}
__device__ __forceinline__ float fast_sigmoid(float x) {
    return rcp_fast(1.0f + __expf(-x));
}

// ============ prep: split weights to bf16 hi/lo and pack in MFMA frag order.
// Stream per layer = 28 slots x 1024B.  Slot s, lane l -> 16B at s*1024 + l*16.
//  s 0..7 : conv A hi   (s = rt*2+q)  A[m=16rt+(l&15)][k=32q+8*(l>>4)+j]
//  s 8..15: conv A lo
//  s 16,17: skip A hi   (s-16 = rt2)  W1[o=16rt2+(l&15)][c=8*(l>>4)+j]
//  s 18,19: skip A lo
//  s 20..23: bias f/g (f32x4 per lane) bd[16rt + 4*(l>>4) + r]
//  s 24,25: bias skip                  b1[16rt2 + 4*(l>>4) + r]
__global__ __launch_bounds__(64) void k_prep(const float* __restrict__ Wd,
                                             const float* __restrict__ bd,
                                             const float* __restrict__ W1,
                                             const float* __restrict__ b1,
                                             unsigned short* __restrict__ stream) {
    int i = blockIdx.x;
    int l = threadIdx.x;
    int p = l & 15, h4 = l >> 4;
    const float* wd  = Wd + (size_t)i * 64 * 64;   // (64,32,2)
    const float* w1  = W1 + (size_t)i * 1024;      // (32,32)
    const float* bdp = bd + (size_t)i * 64;
    const float* b1p = b1 + (size_t)i * 32;
    unsigned short* out = stream + (size_t)i * (28672 / 2);

    for (int rt = 0; rt < 4; ++rt)
        for (int q = 0; q < 2; ++q) {
            int slot = rt * 2 + q;
            for (int j = 0; j < 8; ++j) {
                int m = 16 * rt + p;
                int k = 32 * q + 8 * h4 + j;
                int c = k & 31, tap = k >> 5;
                float w = wd[m * 64 + c * 2 + tap];
                unsigned short hi = f2bf(w);
                out[(size_t)slot * 512 + l * 8 + j] = hi;
                out[(size_t)(8 + slot) * 512 + l * 8 + j] = f2bf(w - bf2f(hi));
            }
        }
    for (int rt2 = 0; rt2 < 2; ++rt2)
        for (int j = 0; j < 8; ++j) {
            int o = 16 * rt2 + p, c = 8 * h4 + j;
            float w = w1[o * 32 + c];
            unsigned short hi = f2bf(w);
            out[(size_t)(16 + rt2) * 512 + l * 8 + j] = hi;
            out[(size_t)(18 + rt2) * 512 + l * 8 + j] = f2bf(w - bf2f(hi));
        }
    float* outf = (float*)stream + (size_t)i * (28672 / 4);
    for (int rt = 0; rt < 4; ++rt)
        for (int r = 0; r < 4; ++r)
            outf[(size_t)(20 + rt) * 256 + l * 4 + r] = bdp[16 * rt + 4 * h4 + r];
    for (int rt2 = 0; rt2 < 2; ++rt2)
        for (int r = 0; r < 4; ++r)
            outf[(size_t)(24 + rt2) * 256 + l * 4 + r] = b1p[16 * rt2 + 4 * h4 + r];
}

// ============ initial conv (1->32, K=2, dil=1); writes hi/lo planes (b,t,c); zeros pooled
__global__ __launch_bounds__(256) void k_init(const float* __restrict__ x,
                                              const float* __restrict__ W0,
                                              const float* __restrict__ b0,
                                              unsigned short* __restrict__ hhi,
                                              unsigned short* __restrict__ hlo,
                                              float* __restrict__ pooled) {
    int idx = blockIdx.x * 256 + threadIdx.x;
    int b = idx >> 13, t = idx & (SEQ - 1);
    float xt = x[b * SEQ + t];
    float xm = (t > 0) ? x[b * SEQ + t - 1] : 0.0f;
    __align__(16) unsigned short hi[CH], lo[CH];
#pragma unroll
    for (int c = 0; c < CH; ++c) {
        float v = W0[c * 2] * xm + W0[c * 2 + 1] * xt + b0[c];
        hi[c] = f2bf(v);
        lo[c] = f2bf(v - bf2f(hi[c]));
    }
    size_t base = (size_t)idx * CH;
#pragma unroll
    for (int k = 0; k < 4; ++k) {
        *(short8*)(hhi + base + 8 * k) = *(const short8*)(hi + 8 * k);
        *(short8*)(hlo + base + 8 * k) = *(const short8*)(lo + 8 * k);
    }
    if (idx < BATCH * CH * 4) pooled[idx] = 0.0f;
}

// ============ one WaveNet block via split-bf16 MFMA.
// Wave handles 64 positions (4 subtiles of 16). WG = 4 waves = 256 pos.
__global__ __launch_bounds__(256, 2) void k_layer(
        const unsigned short* __restrict__ in_hi,
        const unsigned short* __restrict__ in_lo,
        unsigned short* __restrict__ out_hi,
        unsigned short* __restrict__ out_lo,
        const unsigned short* __restrict__ frag,
        int dil) {
    int tid = threadIdx.x;
    int lane = tid & 63, wave = tid >> 6;
    int p = lane & 15, h4 = lane >> 4;
    int b = blockIdx.x >> 5;
    int tbase = (blockIdx.x & 31) * 256 + wave * 64;

    // weight fragments: each slot read is a wave-contiguous 1KB dwordx4 load
    const short8* fs = (const short8*)frag;
    short8 Ah[4][2], Al[4][2], Sh[2], Sl[2];
#pragma unroll
    for (int rt = 0; rt < 4; ++rt)
#pragma unroll
        for (int q = 0; q < 2; ++q) {
            Ah[rt][q] = fs[(rt * 2 + q) * 64 + lane];
            Al[rt][q] = fs[(8 + rt * 2 + q) * 64 + lane];
        }
#pragma unroll
    for (int rt2 = 0; rt2 < 2; ++rt2) {
        Sh[rt2] = fs[(16 + rt2) * 64 + lane];
        Sl[rt2] = fs[(18 + rt2) * 64 + lane];
    }
    const f32x4* ff = (const f32x4*)frag;
    f32x4 bFG[4], bS[2];
#pragma unroll
    for (int rt = 0; rt < 4; ++rt) bFG[rt] = ff[(20 + rt) * 64 + lane];
#pragma unroll
    for (int rt2 = 0; rt2 < 2; ++rt2) bS[rt2] = ff[(24 + rt2) * 64 + lane];

    // per-wave gated bounce buffer: [hi/lo][row p][40 shorts] (80B stride: 16-aligned,
    // bank spread p*20 mod 32 -> <=2-way conflicts which are free)
    __shared__ __align__(16) unsigned short gbuf[4][2][16][40];

    const unsigned short* pin_hi = in_hi + (size_t)b * SEQ * CH;
    const unsigned short* pin_lo = in_lo + (size_t)b * SEQ * CH;
    unsigned short* pout_hi = out_hi + (size_t)b * SEQ * CH;
    unsigned short* pout_lo = out_lo + (size_t)b * SEQ * CH;

    const short8 zero8 = {0, 0, 0, 0, 0, 0, 0, 0};

#pragma unroll 1
    for (int s = 0; s < 4; ++s) {
        int t0 = tbase + s * 16;
        int tp = t0 + p;
        int tq = tp - dil;
        bool ok = (tq >= 0);
        int tqc = ok ? tq : 0;
        // B frags: channels 8*h4..+7 at position tp (q=1) and tp-d (q=0)
        short8 bh1 = *(const short8*)(pin_hi + (size_t)tp * CH + 8 * h4);
        short8 bl1 = *(const short8*)(pin_lo + (size_t)tp * CH + 8 * h4);
        short8 bh0 = *(const short8*)(pin_hi + (size_t)tqc * CH + 8 * h4);
        short8 bl0 = *(const short8*)(pin_lo + (size_t)tqc * CH + 8 * h4);
        if (!ok) { bh0 = zero8; bl0 = zero8; }

        f32x4 acc[4];
#pragma unroll
        for (int rt = 0; rt < 4; ++rt) {
            f32x4 a = bFG[rt];
            a = __builtin_amdgcn_mfma_f32_16x16x32_bf16(Ah[rt][0], bh0, a, 0, 0, 0);
            a = __builtin_amdgcn_mfma_f32_16x16x32_bf16(Ah[rt][1], bh1, a, 0, 0, 0);
            a = __builtin_amdgcn_mfma_f32_16x16x32_bf16(Ah[rt][0], bl0, a, 0, 0, 0);
            a = __builtin_amdgcn_mfma_f32_16x16x32_bf16(Ah[rt][1], bl1, a, 0, 0, 0);
            a = __builtin_amdgcn_mfma_f32_16x16x32_bf16(Al[rt][0], bh0, a, 0, 0, 0);
            a = __builtin_amdgcn_mfma_f32_16x16x32_bf16(Al[rt][1], bh1, a, 0, 0, 0);
            acc[rt] = a;
        }

        // gated = tanh(f)*sigmoid(g); split to hi/lo; bounce through LDS to
        // re-fragment from C-layout (row=ch) to B-layout (k=ch)
#pragma unroll
        for (int rt = 0; rt < 2; ++rt) {
            __align__(8) unsigned short g4h[4], g4l[4];
#pragma unroll
            for (int r = 0; r < 4; ++r) {
                float f = acc[rt][r], g = acc[rt + 2][r];
                float gated = fast_tanh(f) * fast_sigmoid(g);
                unsigned short hh = f2bf(gated);
                g4h[r] = hh;
                g4l[r] = f2bf(gated - bf2f(hh));
            }
            *(short4v*)&gbuf[wave][0][p][16 * rt + 4 * h4] = *(const short4v*)g4h;
            *(short4v*)&gbuf[wave][1][p][16 * rt + 4 * h4] = *(const short4v*)g4l;
        }
        asm volatile("s_waitcnt lgkmcnt(0)" ::: "memory");
        __builtin_amdgcn_sched_barrier(0);
        short8 Bgh = *(const short8*)&gbuf[wave][0][p][8 * h4];
        short8 Bgl = *(const short8*)&gbuf[wave][1][p][8 * h4];

        f32x4 sacc[2];
#pragma unroll
        for (int rt2 = 0; rt2 < 2; ++rt2) {
            f32x4 a = bS[rt2];
            a = __builtin_amdgcn_mfma_f32_16x16x32_bf16(Sh[rt2], Bgh, a, 0, 0, 0);
            a = __builtin_amdgcn_mfma_f32_16x16x32_bf16(Sh[rt2], Bgl, a, 0, 0, 0);
            a = __builtin_amdgcn_mfma_f32_16x16x32_bf16(Sl[rt2], Bgh, a, 0, 0, 0);
            sacc[rt2] = a;
        }

        // residual: hnew = (hi+lo) + skip; split-store
#pragma unroll
        for (int rt2 = 0; rt2 < 2; ++rt2) {
            const unsigned short* ph = pin_hi + (size_t)tp * CH + 16 * rt2 + 4 * h4;
            const unsigned short* pl = pin_lo + (size_t)tp * CH + 16 * rt2 + 4 * h4;
            short4v hh = *(const short4v*)ph;
            short4v hl = *(const short4v*)pl;
            __align__(8) unsigned short oh[4], ol[4];
#pragma unroll
            for (int r = 0; r < 4; ++r) {
                float hv = bf2f((unsigned short)hh[r]) + bf2f((unsigned short)hl[r]);
                float hn = hv + sacc[rt2][r];
                unsigned short nh = f2bf(hn);
                oh[r] = nh;
                ol[r] = f2bf(hn - bf2f(nh));
            }
            *(short4v*)(pout_hi + (size_t)tp * CH + 16 * rt2 + 4 * h4) = *(const short4v*)oh;
            *(short4v*)(pout_lo + (size_t)tp * CH + 16 * rt2 + 4 * h4) = *(const short4v*)ol;
        }
    }
}

// ============ relu(h_fin - h0(recomputed)) -> Wf -> relu -> chunk max -> atomicMax
__global__ __launch_bounds__(256) void k_final1(
        const unsigned short* __restrict__ hf_hi,
        const unsigned short* __restrict__ hf_lo,
        const float* __restrict__ x,
        const float* __restrict__ W0,
        const float* __restrict__ b0,
        const float* __restrict__ Wf,
        const float* __restrict__ bf,
        float* __restrict__ pooled) {
    int blk = blockIdx.x;
    int b = blk >> 5;
    int chunk = blk & 31;
    int q = chunk >> 3;
    int t = chunk * 256 + threadIdx.x;

    float xt = x[b * SEQ + t];
    float xm = (t > 0) ? x[b * SEQ + t - 1] : 0.0f;
    const unsigned short* ph = hf_hi + ((size_t)b * SEQ + t) * CH;
    const unsigned short* pl = hf_lo + ((size_t)b * SEQ + t) * CH;
    short8 vh[4], vl[4];
#pragma unroll
    for (int k = 0; k < 4; ++k) {
        vh[k] = *(const short8*)(ph + 8 * k);
        vl[k] = *(const short8*)(pl + 8 * k);
    }
    float r[CH];
#pragma unroll
    for (int k = 0; k < 4; ++k)
#pragma unroll
        for (int j = 0; j < 8; ++j) {
            int c = 8 * k + j;
            float h0 = W0[c * 2] * xm + W0[c * 2 + 1] * xt + b0[c];
            float hf = bf2f((unsigned short)vh[k][j]) + bf2f((unsigned short)vl[k][j]);
            r[c] = fmaxf(hf - h0, 0.0f);
        }

    float y[CH];
#pragma unroll 1
    for (int o = 0; o < CH; ++o) {
        const float* w = Wf + o * CH;
        float a0 = bf[o], a1 = 0.0f, a2 = 0.0f, a3 = 0.0f;
#pragma unroll
        for (int c = 0; c < CH; c += 4) {
            a0 += w[c + 0] * r[c + 0];
            a1 += w[c + 1] * r[c + 1];
            a2 += w[c + 2] * r[c + 2];
            a3 += w[c + 3] * r[c + 3];
        }
        y[o] = fmaxf((a0 + a1) + (a2 + a3), 0.0f);
    }

#pragma unroll
    for (int o = 0; o < CH; ++o) {
#pragma unroll
        for (int off = 32; off >= 1; off >>= 1)
            y[o] = fmaxf(y[o], __shfl_xor(y[o], off));
    }

    __shared__ float red[4 * CH];
    int wave = threadIdx.x >> 6, lane = threadIdx.x & 63;
    if (lane == 0) {
#pragma unroll
        for (int o = 0; o < CH; ++o) red[wave * CH + o] = y[o];
    }
    __syncthreads();
    if (threadIdx.x < CH) {
        float m = fmaxf(fmaxf(red[threadIdx.x], red[CH + threadIdx.x]),
                        fmaxf(red[2 * CH + threadIdx.x], red[3 * CH + threadIdx.x]));
        atomicMax((unsigned int*)&pooled[b * (CH * 4) + threadIdx.x * 4 + q],
                  __float_as_uint(m));
    }
}

// ============ final MLP
__global__ __launch_bounds__(1024) void k_final2(const float* __restrict__ pooled,
                                                 const float* __restrict__ fW1,
                                                 const float* __restrict__ fb1,
                                                 const float* __restrict__ fW2,
                                                 const float* __restrict__ fb2,
                                                 float* __restrict__ out) {
    __shared__ float y1[BATCH * 64];
    int tid = threadIdx.x;
    int b = tid >> 6, o = tid & 63;
    float acc = fb1[o];
#pragma unroll
    for (int j = 0; j < 128; ++j) acc += fW1[o * 128 + j] * pooled[b * 128 + j];
    y1[b * 64 + o] = fmaxf(acc, 0.0f);
    __syncthreads();
    if (tid < BATCH * 10) {
        int bb = tid / 10, o2 = tid % 10;
        float a2 = fb2[o2];
#pragma unroll
        for (int j = 0; j < 64; ++j) a2 += fW2[o2 * 64 + j] * y1[bb * 64 + j];
        out[bb * 10 + o2] = a2;
    }
}

extern "C" void kernel_launch(void* const* d_in, const int* in_sizes, int n_in,
                              void* d_out, int out_size, void* d_ws, size_t ws_size,
                              hipStream_t stream) {
    const float* x   = (const float*)d_in[0];
    const float* W0  = (const float*)d_in[1];
    const float* b0  = (const float*)d_in[2];
    const float* Wd  = (const float*)d_in[3];
    const float* bd  = (const float*)d_in[4];
    const float* W1  = (const float*)d_in[5];
    const float* b1  = (const float*)d_in[6];
    const float* Wf  = (const float*)d_in[7];
    const float* bf  = (const float*)d_in[8];
    const float* fW1 = (const float*)d_in[9];
    const float* fb1 = (const float*)d_in[10];
    const float* fW2 = (const float*)d_in[11];
    const float* fb2 = (const float*)d_in[12];
    float* out = (float*)d_out;

    const size_t HS = (size_t)BATCH * SEQ * CH;        // 4M elems
    unsigned short* Ahi = (unsigned short*)d_ws;       // 8 MB each plane
    unsigned short* Alo = Ahi + HS;
    unsigned short* Bhi = Alo + HS;
    unsigned short* Blo = Bhi + HS;
    unsigned short* wstream = Blo + HS;                // 24 * 14336 shorts
    float* pooled = (float*)(wstream + (size_t)NB * 14336);

    k_prep<<<NB, 64, 0, stream>>>(Wd, bd, W1, b1, wstream);
    k_init<<<512, 256, 0, stream>>>(x, W0, b0, Ahi, Alo, pooled);

    for (int i = 0; i < NB; ++i) {
        const unsigned short* ih = (i & 1) ? Bhi : Ahi;
        const unsigned short* il = (i & 1) ? Blo : Alo;
        unsigned short* oh = (i & 1) ? Ahi : Bhi;
        unsigned short* ol = (i & 1) ? Alo : Blo;
        k_layer<<<512, 256, 0, stream>>>(ih, il, oh, ol,
                                         wstream + (size_t)i * 14336, 1 << (i & 7));
    }
    // after 24 layers (last i=23 odd writes A): h_fin = A planes
    k_final1<<<512, 256, 0, stream>>>(Ahi, Alo, x, W0, b0, Wf, bf, pooled);
    k_final2<<<1, 1024, 0, stream>>>(pooled, fW1, fb1, fW2, fb2, out);
}

// Round 5
// 392.811 us; speedup vs baseline: 4.9360x; 1.1327x over previous
//
#include <hip/hip_runtime.h>

#define BATCH 16
#define SEQ 8192
#define CH 32
#define NB 24

typedef __attribute__((ext_vector_type(8))) short short8;
typedef __attribute__((ext_vector_type(4))) short short4v;
typedef __attribute__((ext_vector_type(4))) float f32x4;

__device__ __forceinline__ unsigned short f2bf(float x) {
    unsigned int u = __float_as_uint(x);
    unsigned int r = (u + 0x7FFFu + ((u >> 16) & 1u)) >> 16;
    return (unsigned short)r;
}
__device__ __forceinline__ float bf2f(unsigned short h) {
    return __uint_as_float(((unsigned int)h) << 16);
}

__device__ __forceinline__ float rcp_fast(float x) { return __builtin_amdgcn_rcpf(x); }

__device__ __forceinline__ float fast_tanh(float x) {
    float ax = fabsf(x);
    float e = __expf(-2.0f * ax);
    float t = (1.0f - e) * rcp_fast(1.0f + e);
    return copysignf(t, x);
}
__device__ __forceinline__ float fast_sigmoid(float x) {
    return rcp_fast(1.0f + __expf(-x));
}

// ============ prep: split weights to bf16 hi/lo, pack in MFMA frag order (verified r3)
__global__ __launch_bounds__(64) void k_prep(const float* __restrict__ Wd,
                                             const float* __restrict__ bd,
                                             const float* __restrict__ W1,
                                             const float* __restrict__ b1,
                                             unsigned short* __restrict__ stream) {
    int i = blockIdx.x;
    int l = threadIdx.x;
    int p = l & 15, h4 = l >> 4;
    const float* wd  = Wd + (size_t)i * 64 * 64;
    const float* w1  = W1 + (size_t)i * 1024;
    const float* bdp = bd + (size_t)i * 64;
    const float* b1p = b1 + (size_t)i * 32;
    unsigned short* out = stream + (size_t)i * (28672 / 2);

    for (int rt = 0; rt < 4; ++rt)
        for (int q = 0; q < 2; ++q) {
            int slot = rt * 2 + q;
            for (int j = 0; j < 8; ++j) {
                int m = 16 * rt + p;
                int k = 32 * q + 8 * h4 + j;
                int c = k & 31, tap = k >> 5;
                float w = wd[m * 64 + c * 2 + tap];
                unsigned short hi = f2bf(w);
                out[(size_t)slot * 512 + l * 8 + j] = hi;
                out[(size_t)(8 + slot) * 512 + l * 8 + j] = f2bf(w - bf2f(hi));
            }
        }
    for (int rt2 = 0; rt2 < 2; ++rt2)
        for (int j = 0; j < 8; ++j) {
            int o = 16 * rt2 + p, c = 8 * h4 + j;
            float w = w1[o * 32 + c];
            unsigned short hi = f2bf(w);
            out[(size_t)(16 + rt2) * 512 + l * 8 + j] = hi;
            out[(size_t)(18 + rt2) * 512 + l * 8 + j] = f2bf(w - bf2f(hi));
        }
    float* outf = (float*)stream + (size_t)i * (28672 / 4);
    for (int rt = 0; rt < 4; ++rt)
        for (int r = 0; r < 4; ++r)
            outf[(size_t)(20 + rt) * 256 + l * 4 + r] = bdp[16 * rt + 4 * h4 + r];
    for (int rt2 = 0; rt2 < 2; ++rt2)
        for (int r = 0; r < 4; ++r)
            outf[(size_t)(24 + rt2) * 256 + l * 4 + r] = b1p[16 * rt2 + 4 * h4 + r];
}

// ============ initial conv (1->32, K=2, dil=1); hi/lo planes (b,t,c); zero pooled
__global__ __launch_bounds__(256) void k_init(const float* __restrict__ x,
                                              const float* __restrict__ W0,
                                              const float* __restrict__ b0,
                                              unsigned short* __restrict__ hhi,
                                              unsigned short* __restrict__ hlo,
                                              float* __restrict__ pooled) {
    int idx = blockIdx.x * 256 + threadIdx.x;
    int b = idx >> 13, t = idx & (SEQ - 1);
    float xt = x[b * SEQ + t];
    float xm = (t > 0) ? x[b * SEQ + t - 1] : 0.0f;
    __align__(16) unsigned short hi[CH], lo[CH];
#pragma unroll
    for (int c = 0; c < CH; ++c) {
        float v = W0[c * 2] * xm + W0[c * 2 + 1] * xt + b0[c];
        hi[c] = f2bf(v);
        lo[c] = f2bf(v - bf2f(hi[c]));
    }
    size_t base = (size_t)idx * CH;
#pragma unroll
    for (int k = 0; k < 4; ++k) {
        *(short8*)(hhi + base + 8 * k) = *(const short8*)(hi + 8 * k);
        *(short8*)(hlo + base + 8 * k) = *(const short8*)(lo + 8 * k);
    }
    if (idx < BATCH * CH * 4) pooled[idx] = 0.0f;
}

// ============ fused 8-layer stack. Block: 512 thr (8 waves), tile OUT=512,
// halo 256 (sum dil = 255), worked W=768. h resident in LDS as bf16 hi/lo,
// 80B-padded rows (<=2-way bank conflicts). Two-phase per layer (read-all ->
// sync -> write-all) for cross-wave RAW safety. Grid 256 = 1 block/CU.
// CAUSAL FIX (r4 bug): zero-gate must use GLOBAL source position, not LDS
// index — ghost slots (global t<0) evolve nonzero values in-place and must
// never be read as conv sources.
__global__ __launch_bounds__(512, 2) void k_stack(
        const unsigned short* __restrict__ in_hi,
        const unsigned short* __restrict__ in_lo,
        unsigned short* __restrict__ out_hi,
        unsigned short* __restrict__ out_lo,
        const unsigned short* __restrict__ wstream,
        int stack) {
    __shared__ __align__(16) unsigned short lhi[768 * 40];
    __shared__ __align__(16) unsigned short llo[768 * 40];
    __shared__ __align__(16) unsigned short gbuf[8][2][16][40];

    int tid = threadIdx.x;
    int lane = tid & 63, wave = tid >> 6;
    int p = lane & 15, h4 = lane >> 4;
    int bb = blockIdx.x >> 4;
    int T0 = (blockIdx.x & 15) * 512;

    const unsigned short* pin_hi = in_hi + (size_t)bb * SEQ * CH;
    const unsigned short* pin_lo = in_lo + (size_t)bb * SEQ * CH;
    unsigned short* pout_hi = out_hi + (size_t)bb * SEQ * CH;
    unsigned short* pout_lo = out_lo + (size_t)bb * SEQ * CH;

    const short8 zero8 = {0, 0, 0, 0, 0, 0, 0, 0};

    // ---- load tile [T0-256, T0+512) into LDS (zeros for t<0: causal pad)
    for (int i = tid; i < 768; i += 512) {
        int t = T0 - 256 + i;
        if (t >= 0) {
#pragma unroll
            for (int k = 0; k < 4; ++k) {
                *(short8*)&lhi[i * 40 + 8 * k] = *(const short8*)(pin_hi + (size_t)t * CH + 8 * k);
                *(short8*)&llo[i * 40 + 8 * k] = *(const short8*)(pin_lo + (size_t)t * CH + 8 * k);
            }
        } else {
#pragma unroll
            for (int k = 0; k < 4; ++k) {
                *(short8*)&lhi[i * 40 + 8 * k] = zero8;
                *(short8*)&llo[i * 40 + 8 * k] = zero8;
            }
        }
    }
    __syncthreads();

#pragma unroll 1
    for (int l = 0; l < 8; ++l) {
        int dil = 1 << l;
        const unsigned short* frag = wstream + (size_t)(8 * stack + l) * 14336;
        const short8* fs = (const short8*)frag;
        short8 Ah[4][2], Al[4][2], Sh[2], Sl[2];
#pragma unroll
        for (int rt = 0; rt < 4; ++rt)
#pragma unroll
            for (int q = 0; q < 2; ++q) {
                Ah[rt][q] = fs[(rt * 2 + q) * 64 + lane];
                Al[rt][q] = fs[(8 + rt * 2 + q) * 64 + lane];
            }
#pragma unroll
        for (int rt2 = 0; rt2 < 2; ++rt2) {
            Sh[rt2] = fs[(16 + rt2) * 64 + lane];
            Sl[rt2] = fs[(18 + rt2) * 64 + lane];
        }
        const f32x4* ff = (const f32x4*)frag;
        f32x4 bFG[4], bS[2];
#pragma unroll
        for (int rt = 0; rt < 4; ++rt) bFG[rt] = ff[(20 + rt) * 64 + lane];
#pragma unroll
        for (int rt2 = 0; rt2 < 2; ++rt2) bS[rt2] = ff[(24 + rt2) * 64 + lane];

        float hnew[6][2][4];

        // ---- phase 1: everyone reads OLD h, computes new h into registers
#pragma unroll
        for (int s6 = 0; s6 < 6; ++s6) {
            int tpos = wave * 96 + s6 * 16 + p;
            int tq = tpos - dil;
            // causal gate on GLOBAL source position (r4 fix). Ghost-region
            // consumers (tq<0 with ok=true at interior tiles) are below the
            // corruption watermark and never influence the stored output.
            bool ok = (T0 - 256 + tq >= 0);
            int tqc = (tq > 0) ? tq : 0;

            short8 bh1 = *(const short8*)&lhi[tpos * 40 + 8 * h4];
            short8 bl1 = *(const short8*)&llo[tpos * 40 + 8 * h4];
            short8 bh0 = *(const short8*)&lhi[tqc * 40 + 8 * h4];
            short8 bl0 = *(const short8*)&llo[tqc * 40 + 8 * h4];
            if (!ok) { bh0 = zero8; bl0 = zero8; }

            f32x4 acc[4];
#pragma unroll
            for (int rt = 0; rt < 4; ++rt) {
                f32x4 a = bFG[rt];
                a = __builtin_amdgcn_mfma_f32_16x16x32_bf16(Ah[rt][0], bh0, a, 0, 0, 0);
                a = __builtin_amdgcn_mfma_f32_16x16x32_bf16(Ah[rt][1], bh1, a, 0, 0, 0);
                a = __builtin_amdgcn_mfma_f32_16x16x32_bf16(Ah[rt][0], bl0, a, 0, 0, 0);
                a = __builtin_amdgcn_mfma_f32_16x16x32_bf16(Ah[rt][1], bl1, a, 0, 0, 0);
                a = __builtin_amdgcn_mfma_f32_16x16x32_bf16(Al[rt][0], bh0, a, 0, 0, 0);
                a = __builtin_amdgcn_mfma_f32_16x16x32_bf16(Al[rt][1], bh1, a, 0, 0, 0);
                acc[rt] = a;
            }

#pragma unroll
            for (int rt = 0; rt < 2; ++rt) {
                __align__(8) unsigned short g4h[4], g4l[4];
#pragma unroll
                for (int r = 0; r < 4; ++r) {
                    float f = acc[rt][r], g = acc[rt + 2][r];
                    float gated = fast_tanh(f) * fast_sigmoid(g);
                    unsigned short hh = f2bf(gated);
                    g4h[r] = hh;
                    g4l[r] = f2bf(gated - bf2f(hh));
                }
                *(short4v*)&gbuf[wave][0][p][16 * rt + 4 * h4] = *(const short4v*)g4h;
                *(short4v*)&gbuf[wave][1][p][16 * rt + 4 * h4] = *(const short4v*)g4l;
            }
            asm volatile("s_waitcnt lgkmcnt(0)" ::: "memory");
            __builtin_amdgcn_sched_barrier(0);
            short8 Bgh = *(const short8*)&gbuf[wave][0][p][8 * h4];
            short8 Bgl = *(const short8*)&gbuf[wave][1][p][8 * h4];

            f32x4 sacc[2];
#pragma unroll
            for (int rt2 = 0; rt2 < 2; ++rt2) {
                f32x4 a = bS[rt2];
                a = __builtin_amdgcn_mfma_f32_16x16x32_bf16(Sh[rt2], Bgh, a, 0, 0, 0);
                a = __builtin_amdgcn_mfma_f32_16x16x32_bf16(Sh[rt2], Bgl, a, 0, 0, 0);
                a = __builtin_amdgcn_mfma_f32_16x16x32_bf16(Sl[rt2], Bgh, a, 0, 0, 0);
                sacc[rt2] = a;
            }

            // residual: hnew = (hi+lo) + skip  (C-layout: ch = 16rt2+4h4+r, pos = tpos)
#pragma unroll
            for (int rt2 = 0; rt2 < 2; ++rt2) {
                int ch = 16 * rt2 + 4 * h4;
                short4v hh = *(const short4v*)&lhi[tpos * 40 + ch];
                short4v hl = *(const short4v*)&llo[tpos * 40 + ch];
#pragma unroll
                for (int r = 0; r < 4; ++r)
                    hnew[s6][rt2][r] = bf2f((unsigned short)hh[r]) +
                                       bf2f((unsigned short)hl[r]) + sacc[rt2][r];
            }
        }
        __syncthreads();

        // ---- phase 2: write new h (split hi/lo)
#pragma unroll
        for (int s6 = 0; s6 < 6; ++s6) {
            int tpos = wave * 96 + s6 * 16 + p;
#pragma unroll
            for (int rt2 = 0; rt2 < 2; ++rt2) {
                __align__(8) unsigned short oh[4], ol[4];
#pragma unroll
                for (int r = 0; r < 4; ++r) {
                    float v = hnew[s6][rt2][r];
                    unsigned short nh = f2bf(v);
                    oh[r] = nh;
                    ol[r] = f2bf(v - bf2f(nh));
                }
                int ch = 16 * rt2 + 4 * h4;
                *(short4v*)&lhi[tpos * 40 + ch] = *(const short4v*)oh;
                *(short4v*)&llo[tpos * 40 + ch] = *(const short4v*)ol;
            }
        }
        __syncthreads();
    }

    // ---- store output region [T0, T0+512)
    {
        int i = 256 + tid;
        int t = T0 + tid;
#pragma unroll
        for (int k = 0; k < 4; ++k) {
            *(short8*)(pout_hi + (size_t)t * CH + 8 * k) = *(const short8*)&lhi[i * 40 + 8 * k];
            *(short8*)(pout_lo + (size_t)t * CH + 8 * k) = *(const short8*)&llo[i * 40 + 8 * k];
        }
    }
}

// ============ relu(h_fin - h0(recomputed)) -> Wf -> relu -> chunk max -> atomicMax
__global__ __launch_bounds__(256) void k_final1(
        const unsigned short* __restrict__ hf_hi,
        const unsigned short* __restrict__ hf_lo,
        const float* __restrict__ x,
        const float* __restrict__ W0,
        const float* __restrict__ b0,
        const float* __restrict__ Wf,
        const float* __restrict__ bf,
        float* __restrict__ pooled) {
    int blk = blockIdx.x;
    int b = blk >> 5;
    int chunk = blk & 31;
    int q = chunk >> 3;
    int t = chunk * 256 + threadIdx.x;

    float xt = x[b * SEQ + t];
    float xm = (t > 0) ? x[b * SEQ + t - 1] : 0.0f;
    const unsigned short* ph = hf_hi + ((size_t)b * SEQ + t) * CH;
    const unsigned short* pl = hf_lo + ((size_t)b * SEQ + t) * CH;
    short8 vh[4], vl[4];
#pragma unroll
    for (int k = 0; k < 4; ++k) {
        vh[k] = *(const short8*)(ph + 8 * k);
        vl[k] = *(const short8*)(pl + 8 * k);
    }
    float r[CH];
#pragma unroll
    for (int k = 0; k < 4; ++k)
#pragma unroll
        for (int j = 0; j < 8; ++j) {
            int c = 8 * k + j;
            float h0 = W0[c * 2] * xm + W0[c * 2 + 1] * xt + b0[c];
            float hf = bf2f((unsigned short)vh[k][j]) + bf2f((unsigned short)vl[k][j]);
            r[c] = fmaxf(hf - h0, 0.0f);
        }

    float y[CH];
#pragma unroll 1
    for (int o = 0; o < CH; ++o) {
        const float* w = Wf + o * CH;
        float a0 = bf[o], a1 = 0.0f, a2 = 0.0f, a3 = 0.0f;
#pragma unroll
        for (int c = 0; c < CH; c += 4) {
            a0 += w[c + 0] * r[c + 0];
            a1 += w[c + 1] * r[c + 1];
            a2 += w[c + 2] * r[c + 2];
            a3 += w[c + 3] * r[c + 3];
        }
        y[o] = fmaxf((a0 + a1) + (a2 + a3), 0.0f);
    }

#pragma unroll
    for (int o = 0; o < CH; ++o) {
#pragma unroll
        for (int off = 32; off >= 1; off >>= 1)
            y[o] = fmaxf(y[o], __shfl_xor(y[o], off));
    }

    __shared__ float red[4 * CH];
    int wave = threadIdx.x >> 6, lane = threadIdx.x & 63;
    if (lane == 0) {
#pragma unroll
        for (int o = 0; o < CH; ++o) red[wave * CH + o] = y[o];
    }
    __syncthreads();
    if (threadIdx.x < CH) {
        float m = fmaxf(fmaxf(red[threadIdx.x], red[CH + threadIdx.x]),
                        fmaxf(red[2 * CH + threadIdx.x], red[3 * CH + threadIdx.x]));
        atomicMax((unsigned int*)&pooled[b * (CH * 4) + threadIdx.x * 4 + q],
                  __float_as_uint(m));
    }
}

// ============ final MLP
__global__ __launch_bounds__(1024) void k_final2(const float* __restrict__ pooled,
                                                 const float* __restrict__ fW1,
                                                 const float* __restrict__ fb1,
                                                 const float* __restrict__ fW2,
                                                 const float* __restrict__ fb2,
                                                 float* __restrict__ out) {
    __shared__ float y1[BATCH * 64];
    int tid = threadIdx.x;
    int b = tid >> 6, o = tid & 63;
    float acc = fb1[o];
#pragma unroll
    for (int j = 0; j < 128; ++j) acc += fW1[o * 128 + j] * pooled[b * 128 + j];
    y1[b * 64 + o] = fmaxf(acc, 0.0f);
    __syncthreads();
    if (tid < BATCH * 10) {
        int bb = tid / 10, o2 = tid % 10;
        float a2 = fb2[o2];
#pragma unroll
        for (int j = 0; j < 64; ++j) a2 += fW2[o2 * 64 + j] * y1[bb * 64 + j];
        out[bb * 10 + o2] = a2;
    }
}

extern "C" void kernel_launch(void* const* d_in, const int* in_sizes, int n_in,
                              void* d_out, int out_size, void* d_ws, size_t ws_size,
                              hipStream_t stream) {
    const float* x   = (const float*)d_in[0];
    const float* W0  = (const float*)d_in[1];
    const float* b0  = (const float*)d_in[2];
    const float* Wd  = (const float*)d_in[3];
    const float* bd  = (const float*)d_in[4];
    const float* W1  = (const float*)d_in[5];
    const float* b1  = (const float*)d_in[6];
    const float* Wf  = (const float*)d_in[7];
    const float* bf  = (const float*)d_in[8];
    const float* fW1 = (const float*)d_in[9];
    const float* fb1 = (const float*)d_in[10];
    const float* fW2 = (const float*)d_in[11];
    const float* fb2 = (const float*)d_in[12];
    float* out = (float*)d_out;

    const size_t HS = (size_t)BATCH * SEQ * CH;
    unsigned short* Ahi = (unsigned short*)d_ws;
    unsigned short* Alo = Ahi + HS;
    unsigned short* Bhi = Alo + HS;
    unsigned short* Blo = Bhi + HS;
    unsigned short* wstream = Blo + HS;
    float* pooled = (float*)(wstream + (size_t)NB * 14336);

    k_prep<<<NB, 64, 0, stream>>>(Wd, bd, W1, b1, wstream);
    k_init<<<512, 256, 0, stream>>>(x, W0, b0, Ahi, Alo, pooled);

    // stack 0: A -> B ; stack 1: B -> A ; stack 2: A -> B
    k_stack<<<256, 512, 0, stream>>>(Ahi, Alo, Bhi, Blo, wstream, 0);
    k_stack<<<256, 512, 0, stream>>>(Bhi, Blo, Ahi, Alo, wstream, 1);
    k_stack<<<256, 512, 0, stream>>>(Ahi, Alo, Bhi, Blo, wstream, 2);

    k_final1<<<512, 256, 0, stream>>>(Bhi, Blo, x, W0, b0, Wf, bf, pooled);
    k_final2<<<1, 1024, 0, stream>>>(pooled, fW1, fb1, fW2, fb2, out);
}

// Round 8
// 365.677 us; speedup vs baseline: 5.3022x; 1.0742x over previous
//
#include <hip/hip_runtime.h>
#include <hip/hip_bf16.h>

#define BATCH 16
#define SEQ 8192
#define CH 32
#define NB 24

typedef __attribute__((ext_vector_type(8))) short short8;
typedef __attribute__((ext_vector_type(4))) short short4v;
typedef __attribute__((ext_vector_type(4))) float f32x4;

#define LROW 36  // fp32 LDS row stride (144 B: 16B-aligned, dword-bank spread)

__device__ __forceinline__ unsigned short f2bf(float x) {
    __hip_bfloat16 b = __float2bfloat16(x);   // RNE, 1-2 inst on gfx950
    unsigned short u;
    __builtin_memcpy(&u, &b, 2);
    return u;
}
__device__ __forceinline__ float bf2f(unsigned short h) {
    return __uint_as_float(((unsigned int)h) << 16);
}
__device__ __forceinline__ float rcp_fast(float x) { return __builtin_amdgcn_rcpf(x); }

// tanh(f)*sigmoid(g) with a single reciprocal:
// sign(f) * (1-ef) / ((1+ef)*(1+eg)),  ef = exp(-2|f|), eg = exp(-g)
__device__ __forceinline__ float gate_fn(float f, float g) {
    float ef = __expf(-2.0f * fabsf(f));
    float eg = __expf(-g);
    float num = 1.0f - ef;
    float den = (1.0f + ef) * (1.0f + eg);
    return copysignf(num * rcp_fast(den), f);
}

// split fp32 -> bf16 hi + bf16 lo (residual)
__device__ __forceinline__ void split2(float v, unsigned short& h, unsigned short& l) {
    h = f2bf(v);
    l = f2bf(v - bf2f(h));
}

// ============ prep: split weights to bf16 hi/lo, pack in MFMA frag order (verified r3/r5)
__global__ __launch_bounds__(64) void k_prep(const float* __restrict__ Wd,
                                             const float* __restrict__ bd,
                                             const float* __restrict__ W1,
                                             const float* __restrict__ b1,
                                             unsigned short* __restrict__ stream) {
    int i = blockIdx.x;
    int l = threadIdx.x;
    int p = l & 15, h4 = l >> 4;
    const float* wd  = Wd + (size_t)i * 64 * 64;
    const float* w1  = W1 + (size_t)i * 1024;
    const float* bdp = bd + (size_t)i * 64;
    const float* b1p = b1 + (size_t)i * 32;
    unsigned short* out = stream + (size_t)i * (28672 / 2);

    for (int rt = 0; rt < 4; ++rt)
        for (int q = 0; q < 2; ++q) {
            int slot = rt * 2 + q;
            for (int j = 0; j < 8; ++j) {
                int m = 16 * rt + p;
                int k = 32 * q + 8 * h4 + j;
                int c = k & 31, tap = k >> 5;
                float w = wd[m * 64 + c * 2 + tap];
                unsigned short hi = f2bf(w);
                out[(size_t)slot * 512 + l * 8 + j] = hi;
                out[(size_t)(8 + slot) * 512 + l * 8 + j] = f2bf(w - bf2f(hi));
            }
        }
    for (int rt2 = 0; rt2 < 2; ++rt2)
        for (int j = 0; j < 8; ++j) {
            int o = 16 * rt2 + p, c = 8 * h4 + j;
            float w = w1[o * 32 + c];
            unsigned short hi = f2bf(w);
            out[(size_t)(16 + rt2) * 512 + l * 8 + j] = hi;
            out[(size_t)(18 + rt2) * 512 + l * 8 + j] = f2bf(w - bf2f(hi));
        }
    float* outf = (float*)stream + (size_t)i * (28672 / 4);
    for (int rt = 0; rt < 4; ++rt)
        for (int r = 0; r < 4; ++r)
            outf[(size_t)(20 + rt) * 256 + l * 4 + r] = bdp[16 * rt + 4 * h4 + r];
    for (int rt2 = 0; rt2 < 2; ++rt2)
        for (int r = 0; r < 4; ++r)
            outf[(size_t)(24 + rt2) * 256 + l * 4 + r] = b1p[16 * rt2 + 4 * h4 + r];
}

// ============ initial conv (1->32, K=2, dil=1); single fp32 plane (b,t,c); zero pooled
__global__ __launch_bounds__(256) void k_init(const float* __restrict__ x,
                                              const float* __restrict__ W0,
                                              const float* __restrict__ b0,
                                              float* __restrict__ h,
                                              float* __restrict__ pooled) {
    int idx = blockIdx.x * 256 + threadIdx.x;
    int b = idx >> 13, t = idx & (SEQ - 1);
    float xt = x[b * SEQ + t];
    float xm = (t > 0) ? x[b * SEQ + t - 1] : 0.0f;
    __align__(16) float hv[CH];
#pragma unroll
    for (int c = 0; c < CH; ++c)
        hv[c] = W0[c * 2] * xm + W0[c * 2 + 1] * xt + b0[c];
    float* dst = h + (size_t)idx * CH;
#pragma unroll
    for (int k = 0; k < 8; ++k)
        *(f32x4*)(dst + 4 * k) = *(const f32x4*)(hv + 4 * k);
    if (idx < BATCH * CH * 4) pooled[idx] = 0.0f;
}

// ============ fused 8-layer stack, h resident in LDS as fp32.
// Block: 512 thr (8 waves), OUT=512, halo 256 (sum dil=255), W=768 rows.
// Row stride LROW=36 dwords (144B, 16B-aligned). Two-phase per layer.
// bf16 hi/lo fragments for MFMA are derived on the fly from fp32 (read side);
// phase-2 writes are raw f32x4 (no conversion). Causal gate on GLOBAL pos (r5 fix).
__global__ __launch_bounds__(512, 2) void k_stack(
        const float* __restrict__ hin,
        float* __restrict__ hout,
        const unsigned short* __restrict__ wstream,
        int stack) {
    __shared__ __align__(16) float lh[768 * LROW];                  // 110,592 B
    __shared__ __align__(16) unsigned short gbuf[8][2][16][40];     // 20,480 B

    int tid = threadIdx.x;
    int lane = tid & 63, wave = tid >> 6;
    int p = lane & 15, h4 = lane >> 4;
    int bb = blockIdx.x >> 4;
    int T0 = (blockIdx.x & 15) * 512;

    const float* pin = hin + (size_t)bb * SEQ * CH;
    float* pout = hout + (size_t)bb * SEQ * CH;

    const f32x4 zero4 = {0.0f, 0.0f, 0.0f, 0.0f};

    // ---- load tile [T0-256, T0+512) into LDS (zeros for t<0)
    for (int i = tid; i < 768; i += 512) {
        int t = T0 - 256 + i;
        float* dst = &lh[i * LROW];
        if (t >= 0) {
            const float* src = pin + (size_t)t * CH;
#pragma unroll
            for (int k = 0; k < 8; ++k)
                *(f32x4*)(dst + 4 * k) = *(const f32x4*)(src + 4 * k);
        } else {
#pragma unroll
            for (int k = 0; k < 8; ++k)
                *(f32x4*)(dst + 4 * k) = zero4;
        }
    }
    __syncthreads();

#pragma unroll 1
    for (int l = 0; l < 8; ++l) {
        int dil = 1 << l;
        const unsigned short* frag = wstream + (size_t)(8 * stack + l) * 14336;
        const short8* fs = (const short8*)frag;
        short8 Ah[4][2], Al[4][2], Sh[2], Sl[2];
#pragma unroll
        for (int rt = 0; rt < 4; ++rt)
#pragma unroll
            for (int q = 0; q < 2; ++q) {
                Ah[rt][q] = fs[(rt * 2 + q) * 64 + lane];
                Al[rt][q] = fs[(8 + rt * 2 + q) * 64 + lane];
            }
#pragma unroll
        for (int rt2 = 0; rt2 < 2; ++rt2) {
            Sh[rt2] = fs[(16 + rt2) * 64 + lane];
            Sl[rt2] = fs[(18 + rt2) * 64 + lane];
        }
        const f32x4* ff = (const f32x4*)frag;
        f32x4 bFG[4], bS[2];
#pragma unroll
        for (int rt = 0; rt < 4; ++rt) bFG[rt] = ff[(20 + rt) * 64 + lane];
#pragma unroll
        for (int rt2 = 0; rt2 < 2; ++rt2) bS[rt2] = ff[(24 + rt2) * 64 + lane];

        f32x4 hnew[6][2];

        // ---- phase 1: read OLD h (fp32), compute new h into registers
#pragma unroll
        for (int s6 = 0; s6 < 6; ++s6) {
            int tpos = wave * 96 + s6 * 16 + p;
            int tq = tpos - dil;
            bool ok = (T0 - 256 + tq >= 0);   // causal gate on GLOBAL source pos
            int tqc = (tq > 0) ? tq : 0;

            // build bf16 hi/lo B-fragments on the fly from fp32 LDS
            const float* r1 = &lh[tpos * LROW + 8 * h4];
            const float* r0 = &lh[tqc * LROW + 8 * h4];
            f32x4 v1a = *(const f32x4*)r1, v1b = *(const f32x4*)(r1 + 4);
            f32x4 v0a = *(const f32x4*)r0, v0b = *(const f32x4*)(r0 + 4);
            if (!ok) { v0a = zero4; v0b = zero4; }
            short8 bh1, bl1, bh0, bl0;
#pragma unroll
            for (int j = 0; j < 4; ++j) {
                unsigned short hh, ll;
                split2(v1a[j], hh, ll); bh1[j] = (short)hh; bl1[j] = (short)ll;
                split2(v1b[j], hh, ll); bh1[4 + j] = (short)hh; bl1[4 + j] = (short)ll;
                split2(v0a[j], hh, ll); bh0[j] = (short)hh; bl0[j] = (short)ll;
                split2(v0b[j], hh, ll); bh0[4 + j] = (short)hh; bl0[4 + j] = (short)ll;
            }

            f32x4 acc[4];
#pragma unroll
            for (int rt = 0; rt < 4; ++rt) {
                f32x4 a = bFG[rt];
                a = __builtin_amdgcn_mfma_f32_16x16x32_bf16(Ah[rt][0], bh0, a, 0, 0, 0);
                a = __builtin_amdgcn_mfma_f32_16x16x32_bf16(Ah[rt][1], bh1, a, 0, 0, 0);
                a = __builtin_amdgcn_mfma_f32_16x16x32_bf16(Ah[rt][0], bl0, a, 0, 0, 0);
                a = __builtin_amdgcn_mfma_f32_16x16x32_bf16(Ah[rt][1], bl1, a, 0, 0, 0);
                a = __builtin_amdgcn_mfma_f32_16x16x32_bf16(Al[rt][0], bh0, a, 0, 0, 0);
                a = __builtin_amdgcn_mfma_f32_16x16x32_bf16(Al[rt][1], bh1, a, 0, 0, 0);
                acc[rt] = a;
            }

            // gated (merged-rcp) -> split hi/lo -> LDS bounce (C-layout -> B-layout)
#pragma unroll
            for (int rt = 0; rt < 2; ++rt) {
                __align__(8) unsigned short g4h[4], g4l[4];
#pragma unroll
                for (int r = 0; r < 4; ++r) {
                    float gated = gate_fn(acc[rt][r], acc[rt + 2][r]);
                    split2(gated, g4h[r], g4l[r]);
                }
                *(short4v*)&gbuf[wave][0][p][16 * rt + 4 * h4] = *(const short4v*)g4h;
                *(short4v*)&gbuf[wave][1][p][16 * rt + 4 * h4] = *(const short4v*)g4l;
            }
            asm volatile("s_waitcnt lgkmcnt(0)" ::: "memory");
            __builtin_amdgcn_sched_barrier(0);
            short8 Bgh = *(const short8*)&gbuf[wave][0][p][8 * h4];
            short8 Bgl = *(const short8*)&gbuf[wave][1][p][8 * h4];

            f32x4 sacc[2];
#pragma unroll
            for (int rt2 = 0; rt2 < 2; ++rt2) {
                f32x4 a = bS[rt2];
                a = __builtin_amdgcn_mfma_f32_16x16x32_bf16(Sh[rt2], Bgh, a, 0, 0, 0);
                a = __builtin_amdgcn_mfma_f32_16x16x32_bf16(Sh[rt2], Bgl, a, 0, 0, 0);
                a = __builtin_amdgcn_mfma_f32_16x16x32_bf16(Sl[rt2], Bgh, a, 0, 0, 0);
                sacc[rt2] = a;
            }

            // residual: hnew = h(fp32) + skip   (C-layout: ch = 16rt2+4h4+r)
#pragma unroll
            for (int rt2 = 0; rt2 < 2; ++rt2) {
                f32x4 hold = *(const f32x4*)&lh[tpos * LROW + 16 * rt2 + 4 * h4];
                hnew[s6][rt2] = hold + sacc[rt2];
            }
        }
        __syncthreads();

        // ---- phase 2: write new h (raw fp32, no conversion)
#pragma unroll
        for (int s6 = 0; s6 < 6; ++s6) {
            int tpos = wave * 96 + s6 * 16 + p;
#pragma unroll
            for (int rt2 = 0; rt2 < 2; ++rt2)
                *(f32x4*)&lh[tpos * LROW + 16 * rt2 + 4 * h4] = hnew[s6][rt2];
        }
        __syncthreads();
    }

    // ---- store output region [T0, T0+512)
    {
        int i = 256 + tid;
        int t = T0 + tid;
        const float* src = &lh[i * LROW];
        float* dst = pout + (size_t)t * CH;
#pragma unroll
        for (int k = 0; k < 8; ++k)
            *(f32x4*)(dst + 4 * k) = *(const f32x4*)(src + 4 * k);
    }
}

// ============ relu(h_fin - h0(recomputed)) -> Wf -> relu -> chunk max -> atomicMax
__global__ __launch_bounds__(256) void k_final1(
        const float* __restrict__ hfin,
        const float* __restrict__ x,
        const float* __restrict__ W0,
        const float* __restrict__ b0,
        const float* __restrict__ Wf,
        const float* __restrict__ bf,
        float* __restrict__ pooled) {
    int blk = blockIdx.x;
    int b = blk >> 5;
    int chunk = blk & 31;
    int q = chunk >> 3;
    int t = chunk * 256 + threadIdx.x;

    float xt = x[b * SEQ + t];
    float xm = (t > 0) ? x[b * SEQ + t - 1] : 0.0f;
    const float* ph = hfin + ((size_t)b * SEQ + t) * CH;
    f32x4 v[8];
#pragma unroll
    for (int k = 0; k < 8; ++k) v[k] = *(const f32x4*)(ph + 4 * k);

    float r[CH];
#pragma unroll
    for (int k = 0; k < 8; ++k)
#pragma unroll
        for (int j = 0; j < 4; ++j) {
            int c = 4 * k + j;
            float h0 = W0[c * 2] * xm + W0[c * 2 + 1] * xt + b0[c];
            r[c] = fmaxf(v[k][j] - h0, 0.0f);
        }

    float y[CH];
#pragma unroll 1
    for (int o = 0; o < CH; ++o) {
        const float* w = Wf + o * CH;
        float a0 = bf[o], a1 = 0.0f, a2 = 0.0f, a3 = 0.0f;
#pragma unroll
        for (int c = 0; c < CH; c += 4) {
            a0 += w[c + 0] * r[c + 0];
            a1 += w[c + 1] * r[c + 1];
            a2 += w[c + 2] * r[c + 2];
            a3 += w[c + 3] * r[c + 3];
        }
        y[o] = fmaxf((a0 + a1) + (a2 + a3), 0.0f);
    }

#pragma unroll
    for (int o = 0; o < CH; ++o) {
#pragma unroll
        for (int off = 32; off >= 1; off >>= 1)
            y[o] = fmaxf(y[o], __shfl_xor(y[o], off));
    }

    __shared__ float red[4 * CH];
    int wave = threadIdx.x >> 6, lane = threadIdx.x & 63;
    if (lane == 0) {
#pragma unroll
        for (int o = 0; o < CH; ++o) red[wave * CH + o] = y[o];
    }
    __syncthreads();
    if (threadIdx.x < CH) {
        float m = fmaxf(fmaxf(red[threadIdx.x], red[CH + threadIdx.x]),
                        fmaxf(red[2 * CH + threadIdx.x], red[3 * CH + threadIdx.x]));
        atomicMax((unsigned int*)&pooled[b * (CH * 4) + threadIdx.x * 4 + q],
                  __float_as_uint(m));
    }
}

// ============ final MLP
__global__ __launch_bounds__(1024) void k_final2(const float* __restrict__ pooled,
                                                 const float* __restrict__ fW1,
                                                 const float* __restrict__ fb1,
                                                 const float* __restrict__ fW2,
                                                 const float* __restrict__ fb2,
                                                 float* __restrict__ out) {
    __shared__ float y1[BATCH * 64];
    int tid = threadIdx.x;
    int b = tid >> 6, o = tid & 63;
    float acc = fb1[o];
#pragma unroll
    for (int j = 0; j < 128; ++j) acc += fW1[o * 128 + j] * pooled[b * 128 + j];
    y1[b * 64 + o] = fmaxf(acc, 0.0f);
    __syncthreads();
    if (tid < BATCH * 10) {
        int bb = tid / 10, o2 = tid % 10;
        float a2 = fb2[o2];
#pragma unroll
        for (int j = 0; j < 64; ++j) a2 += fW2[o2 * 64 + j] * y1[bb * 64 + j];
        out[bb * 10 + o2] = a2;
    }
}

extern "C" void kernel_launch(void* const* d_in, const int* in_sizes, int n_in,
                              void* d_out, int out_size, void* d_ws, size_t ws_size,
                              hipStream_t stream) {
    const float* x   = (const float*)d_in[0];
    const float* W0  = (const float*)d_in[1];
    const float* b0  = (const float*)d_in[2];
    const float* Wd  = (const float*)d_in[3];
    const float* bd  = (const float*)d_in[4];
    const float* W1  = (const float*)d_in[5];
    const float* b1  = (const float*)d_in[6];
    const float* Wf  = (const float*)d_in[7];
    const float* bf  = (const float*)d_in[8];
    const float* fW1 = (const float*)d_in[9];
    const float* fb1 = (const float*)d_in[10];
    const float* fW2 = (const float*)d_in[11];
    const float* fb2 = (const float*)d_in[12];
    float* out = (float*)d_out;

    const size_t HS = (size_t)BATCH * SEQ * CH;        // 4M floats = 16 MB
    float* bufA = (float*)d_ws;
    float* bufB = bufA + HS;
    unsigned short* wstream = (unsigned short*)(bufB + HS);   // 24 * 14336 shorts
    float* pooled = (float*)(wstream + (size_t)NB * 14336);

    k_prep<<<NB, 64, 0, stream>>>(Wd, bd, W1, b1, wstream);
    k_init<<<512, 256, 0, stream>>>(x, W0, b0, bufA, pooled);

    // stack 0: A -> B ; stack 1: B -> A ; stack 2: A -> B
    k_stack<<<256, 512, 0, stream>>>(bufA, bufB, wstream, 0);
    k_stack<<<256, 512, 0, stream>>>(bufB, bufA, wstream, 1);
    k_stack<<<256, 512, 0, stream>>>(bufA, bufB, wstream, 2);

    k_final1<<<512, 256, 0, stream>>>(bufB, x, W0, b0, Wf, bf, pooled);
    k_final2<<<1, 1024, 0, stream>>>(pooled, fW1, fb1, fW2, fb2, out);
}

// Round 9
// 328.335 us; speedup vs baseline: 5.9053x; 1.1137x over previous
//
#include <hip/hip_runtime.h>
#include <hip/hip_bf16.h>

#define BATCH 16
#define SEQ 8192
#define CH 32
#define NB 24

typedef __attribute__((ext_vector_type(8))) short short8;
typedef __attribute__((ext_vector_type(4))) short short4v;
typedef __attribute__((ext_vector_type(4))) float f32x4;

#define LROW 36  // fp32 LDS row stride (144 B: 16B-aligned, dword-bank spread)

__device__ __forceinline__ unsigned short f2bf(float x) {
    __hip_bfloat16 b = __float2bfloat16(x);   // RNE
    unsigned short u;
    __builtin_memcpy(&u, &b, 2);
    return u;
}
__device__ __forceinline__ float bf2f(unsigned short h) {
    return __uint_as_float(((unsigned int)h) << 16);
}
__device__ __forceinline__ float rcp_fast(float x) { return __builtin_amdgcn_rcpf(x); }

// tanh(f)*sigmoid(g) with a single reciprocal
__device__ __forceinline__ float gate_fn(float f, float g) {
    float ef = __expf(-2.0f * fabsf(f));
    float eg = __expf(-g);
    float num = 1.0f - ef;
    float den = (1.0f + ef) * (1.0f + eg);
    return copysignf(num * rcp_fast(den), f);
}

__device__ __forceinline__ void split2(float v, unsigned short& h, unsigned short& l) {
    h = f2bf(v);
    l = f2bf(v - bf2f(h));
}

// ============ prep: split weights to bf16 hi/lo, pack in MFMA frag order (verified r3/r5/r8)
// + zero the pooled atomic-max target.
__global__ __launch_bounds__(64) void k_prep(const float* __restrict__ Wd,
                                             const float* __restrict__ bd,
                                             const float* __restrict__ W1,
                                             const float* __restrict__ b1,
                                             unsigned short* __restrict__ stream,
                                             float* __restrict__ pooled) {
    int i = blockIdx.x;
    int l = threadIdx.x;
    int p = l & 15, h4 = l >> 4;
    const float* wd  = Wd + (size_t)i * 64 * 64;
    const float* w1  = W1 + (size_t)i * 1024;
    const float* bdp = bd + (size_t)i * 64;
    const float* b1p = b1 + (size_t)i * 32;
    unsigned short* out = stream + (size_t)i * (28672 / 2);

    for (int g = blockIdx.x * 64 + l; g < BATCH * CH * 4; g += NB * 64)
        pooled[g] = 0.0f;

    for (int rt = 0; rt < 4; ++rt)
        for (int q = 0; q < 2; ++q) {
            int slot = rt * 2 + q;
            for (int j = 0; j < 8; ++j) {
                int m = 16 * rt + p;
                int k = 32 * q + 8 * h4 + j;
                int c = k & 31, tap = k >> 5;
                float w = wd[m * 64 + c * 2 + tap];
                unsigned short hi = f2bf(w);
                out[(size_t)slot * 512 + l * 8 + j] = hi;
                out[(size_t)(8 + slot) * 512 + l * 8 + j] = f2bf(w - bf2f(hi));
            }
        }
    for (int rt2 = 0; rt2 < 2; ++rt2)
        for (int j = 0; j < 8; ++j) {
            int o = 16 * rt2 + p, c = 8 * h4 + j;
            float w = w1[o * 32 + c];
            unsigned short hi = f2bf(w);
            out[(size_t)(16 + rt2) * 512 + l * 8 + j] = hi;
            out[(size_t)(18 + rt2) * 512 + l * 8 + j] = f2bf(w - bf2f(hi));
        }
    float* outf = (float*)stream + (size_t)i * (28672 / 4);
    for (int rt = 0; rt < 4; ++rt)
        for (int r = 0; r < 4; ++r)
            outf[(size_t)(20 + rt) * 256 + l * 4 + r] = bdp[16 * rt + 4 * h4 + r];
    for (int rt2 = 0; rt2 < 2; ++rt2)
        for (int r = 0; r < 4; ++r)
            outf[(size_t)(24 + rt2) * 256 + l * 4 + r] = b1p[16 * rt2 + 4 * h4 + r];
}

// ============ fused 8-layer stack, h resident in LDS as fp32 (r8 structure) +
// r9: (a) double-buffered gbuf software pipeline — the per-s6 lgkmcnt drain now
// lands after the NEXT iteration's 24 conv MFMAs, off the critical path; no
// sched_barrier (all ds ops are compiler-visible; asm memory clobber orders them).
// (b) stack0 builds h0 from x in-LDS (k_init deleted); stack2 runs the
// relu(h-h0)->Wf->relu->maxpool epilogue in-LDS (k_final1 deleted, no h store).
__global__ __launch_bounds__(512, 2) void k_stack(
        const float* __restrict__ hin,
        float* __restrict__ hout,
        const float* __restrict__ x,
        const float* __restrict__ W0,
        const float* __restrict__ b0,
        const float* __restrict__ Wf,
        const float* __restrict__ bf,
        float* __restrict__ pooled,
        const unsigned short* __restrict__ wstream,
        int stack) {
    __shared__ __align__(16) float lh[768 * LROW];                    // 110,592 B
    __shared__ __align__(16) unsigned short gbuf[8][2][2][16][40];    // 40,960 B
    __shared__ float red[8 * CH];                                     // 1,024 B

    int tid = threadIdx.x;
    int lane = tid & 63, wave = tid >> 6;
    int p = lane & 15, h4 = lane >> 4;
    int bb = blockIdx.x >> 4;
    int T0 = (blockIdx.x & 15) * 512;
    bool first = (stack == 0);
    bool last  = (stack == 2);

    const float* pin = hin + (size_t)bb * SEQ * CH;
    float* pout = hout + (size_t)bb * SEQ * CH;
    const float* px = x + (size_t)bb * SEQ;

    const f32x4 zero4 = {0.0f, 0.0f, 0.0f, 0.0f};

    // ---- load tile [T0-256, T0+512) into LDS (zeros for t<0)
    if (first) {
        // build h0 from x: causal conv 1->32, K=2, dil=1
        for (int i = tid; i < 768; i += 512) {
            int t = T0 - 256 + i;
            float* dst = &lh[i * LROW];
            if (t >= 0) {
                float xt = px[t];
                float xm = (t > 0) ? px[t - 1] : 0.0f;
                __align__(16) float hv[CH];
#pragma unroll
                for (int c = 0; c < CH; ++c)
                    hv[c] = W0[c * 2] * xm + W0[c * 2 + 1] * xt + b0[c];
#pragma unroll
                for (int k = 0; k < 8; ++k)
                    *(f32x4*)(dst + 4 * k) = *(const f32x4*)(hv + 4 * k);
            } else {
#pragma unroll
                for (int k = 0; k < 8; ++k)
                    *(f32x4*)(dst + 4 * k) = zero4;
            }
        }
    } else {
        for (int i = tid; i < 768; i += 512) {
            int t = T0 - 256 + i;
            float* dst = &lh[i * LROW];
            if (t >= 0) {
                const float* src = pin + (size_t)t * CH;
#pragma unroll
                for (int k = 0; k < 8; ++k)
                    *(f32x4*)(dst + 4 * k) = *(const f32x4*)(src + 4 * k);
            } else {
#pragma unroll
                for (int k = 0; k < 8; ++k)
                    *(f32x4*)(dst + 4 * k) = zero4;
            }
        }
    }
    __syncthreads();

#pragma unroll 1
    for (int l = 0; l < 8; ++l) {
        int dil = 1 << l;
        const unsigned short* frag = wstream + (size_t)(8 * stack + l) * 14336;
        const short8* fs = (const short8*)frag;
        short8 Ah[4][2], Al[4][2], Sh[2], Sl[2];
#pragma unroll
        for (int rt = 0; rt < 4; ++rt)
#pragma unroll
            for (int q = 0; q < 2; ++q) {
                Ah[rt][q] = fs[(rt * 2 + q) * 64 + lane];
                Al[rt][q] = fs[(8 + rt * 2 + q) * 64 + lane];
            }
#pragma unroll
        for (int rt2 = 0; rt2 < 2; ++rt2) {
            Sh[rt2] = fs[(16 + rt2) * 64 + lane];
            Sl[rt2] = fs[(18 + rt2) * 64 + lane];
        }
        const f32x4* ff = (const f32x4*)frag;
        f32x4 bFG[4], bS[2];
#pragma unroll
        for (int rt = 0; rt < 4; ++rt) bFG[rt] = ff[(20 + rt) * 64 + lane];
#pragma unroll
        for (int rt2 = 0; rt2 < 2; ++rt2) bS[rt2] = ff[(24 + rt2) * 64 + lane];

        f32x4 hnew[6][2];

        // ---- phase 1, software-pipelined:
        // iter i: CONV(i) -> fence -> READ_SKIP(i-1) -> GATE_WRITE(i)
#pragma unroll
        for (int i = 0; i < 7; ++i) {
            f32x4 acc[4];
            if (i < 6) {
                // ---- CONV(i)
                int tpos = wave * 96 + i * 16 + p;
                int tq = tpos - dil;
                bool ok = (T0 - 256 + tq >= 0);   // causal gate on GLOBAL pos (r5)
                int tqc = (tq > 0) ? tq : 0;

                const float* r1 = &lh[tpos * LROW + 8 * h4];
                const float* r0 = &lh[tqc * LROW + 8 * h4];
                f32x4 v1a = *(const f32x4*)r1, v1b = *(const f32x4*)(r1 + 4);
                f32x4 v0a = *(const f32x4*)r0, v0b = *(const f32x4*)(r0 + 4);
                if (!ok) { v0a = zero4; v0b = zero4; }
                short8 bh1, bl1, bh0, bl0;
#pragma unroll
                for (int j = 0; j < 4; ++j) {
                    unsigned short hh, ll;
                    split2(v1a[j], hh, ll); bh1[j] = (short)hh; bl1[j] = (short)ll;
                    split2(v1b[j], hh, ll); bh1[4 + j] = (short)hh; bl1[4 + j] = (short)ll;
                    split2(v0a[j], hh, ll); bh0[j] = (short)hh; bl0[j] = (short)ll;
                    split2(v0b[j], hh, ll); bh0[4 + j] = (short)hh; bl0[4 + j] = (short)ll;
                }
#pragma unroll
                for (int rt = 0; rt < 4; ++rt) {
                    f32x4 a = bFG[rt];
                    a = __builtin_amdgcn_mfma_f32_16x16x32_bf16(Ah[rt][0], bh0, a, 0, 0, 0);
                    a = __builtin_amdgcn_mfma_f32_16x16x32_bf16(Ah[rt][1], bh1, a, 0, 0, 0);
                    a = __builtin_amdgcn_mfma_f32_16x16x32_bf16(Ah[rt][0], bl0, a, 0, 0, 0);
                    a = __builtin_amdgcn_mfma_f32_16x16x32_bf16(Ah[rt][1], bl1, a, 0, 0, 0);
                    a = __builtin_amdgcn_mfma_f32_16x16x32_bf16(Al[rt][0], bh0, a, 0, 0, 0);
                    a = __builtin_amdgcn_mfma_f32_16x16x32_bf16(Al[rt][1], bh1, a, 0, 0, 0);
                    acc[rt] = a;
                }
            }

            if (i > 0) {
                // gbuf writes of slot (i-1) were issued one iteration ago; the
                // 24 MFMAs of CONV(i) covered their latency. Drain + read.
                asm volatile("s_waitcnt lgkmcnt(0)" ::: "memory");
                int ip = i - 1;
                int tposP = wave * 96 + ip * 16 + p;
                short8 Bgh = *(const short8*)&gbuf[wave][ip & 1][0][p][8 * h4];
                short8 Bgl = *(const short8*)&gbuf[wave][ip & 1][1][p][8 * h4];

                f32x4 sacc[2];
#pragma unroll
                for (int rt2 = 0; rt2 < 2; ++rt2) {
                    f32x4 a = bS[rt2];
                    a = __builtin_amdgcn_mfma_f32_16x16x32_bf16(Sh[rt2], Bgh, a, 0, 0, 0);
                    a = __builtin_amdgcn_mfma_f32_16x16x32_bf16(Sh[rt2], Bgl, a, 0, 0, 0);
                    a = __builtin_amdgcn_mfma_f32_16x16x32_bf16(Sl[rt2], Bgh, a, 0, 0, 0);
                    sacc[rt2] = a;
                }
#pragma unroll
                for (int rt2 = 0; rt2 < 2; ++rt2) {
                    f32x4 hold = *(const f32x4*)&lh[tposP * LROW + 16 * rt2 + 4 * h4];
                    hnew[ip][rt2] = hold + sacc[rt2];
                }
            }

            if (i < 6) {
                // ---- GATE_WRITE(i): gate -> split -> gbuf slot i&1
#pragma unroll
                for (int rt = 0; rt < 2; ++rt) {
                    __align__(8) unsigned short g4h[4], g4l[4];
#pragma unroll
                    for (int r = 0; r < 4; ++r) {
                        float gated = gate_fn(acc[rt][r], acc[rt + 2][r]);
                        split2(gated, g4h[r], g4l[r]);
                    }
                    *(short4v*)&gbuf[wave][i & 1][0][p][16 * rt + 4 * h4] = *(const short4v*)g4h;
                    *(short4v*)&gbuf[wave][i & 1][1][p][16 * rt + 4 * h4] = *(const short4v*)g4l;
                }
            }
        }
        __syncthreads();

        // ---- phase 2: write new h (raw fp32)
#pragma unroll
        for (int s6 = 0; s6 < 6; ++s6) {
            int tpos = wave * 96 + s6 * 16 + p;
#pragma unroll
            for (int rt2 = 0; rt2 < 2; ++rt2)
                *(f32x4*)&lh[tpos * LROW + 16 * rt2 + 4 * h4] = hnew[s6][rt2];
        }
        __syncthreads();
    }

    if (!last) {
        // ---- store output region [T0, T0+512)
        int i = 256 + tid;
        int t = T0 + tid;
        const float* src = &lh[i * LROW];
        float* dst = pout + (size_t)t * CH;
#pragma unroll
        for (int k = 0; k < 8; ++k)
            *(f32x4*)(dst + 4 * k) = *(const f32x4*)(src + 4 * k);
    } else {
        // ---- fused finale: relu(h - h0(x)) -> Wf -> relu -> chunk-max -> atomicMax
        int i = 256 + tid;
        int t = T0 + tid;
        int q = (blockIdx.x & 15) >> 2;        // which L/4 quarter
        float xt = px[t];
        float xm = (t > 0) ? px[t - 1] : 0.0f;
        const float* src = &lh[i * LROW];

        float r[CH];
#pragma unroll
        for (int c = 0; c < CH; ++c) {
            float h0 = W0[c * 2] * xm + W0[c * 2 + 1] * xt + b0[c];
            r[c] = fmaxf(src[c] - h0, 0.0f);
        }
        float y[CH];
#pragma unroll 1
        for (int o = 0; o < CH; ++o) {
            const float* w = Wf + o * CH;
            float a0 = bf[o], a1 = 0.0f, a2 = 0.0f, a3 = 0.0f;
#pragma unroll
            for (int c = 0; c < CH; c += 4) {
                a0 += w[c + 0] * r[c + 0];
                a1 += w[c + 1] * r[c + 1];
                a2 += w[c + 2] * r[c + 2];
                a3 += w[c + 3] * r[c + 3];
            }
            y[o] = fmaxf((a0 + a1) + (a2 + a3), 0.0f);
        }
#pragma unroll
        for (int o = 0; o < CH; ++o) {
#pragma unroll
            for (int off = 32; off >= 1; off >>= 1)
                y[o] = fmaxf(y[o], __shfl_xor(y[o], off));
        }
        if (lane == 0) {
#pragma unroll
            for (int o = 0; o < CH; ++o) red[wave * CH + o] = y[o];
        }
        __syncthreads();
        if (tid < CH) {
            float m = red[tid];
#pragma unroll
            for (int w8 = 1; w8 < 8; ++w8) m = fmaxf(m, red[w8 * CH + tid]);
            atomicMax((unsigned int*)&pooled[bb * (CH * 4) + tid * 4 + q],
                      __float_as_uint(m));
        }
    }
}

// ============ final MLP
__global__ __launch_bounds__(1024) void k_final2(const float* __restrict__ pooled,
                                                 const float* __restrict__ fW1,
                                                 const float* __restrict__ fb1,
                                                 const float* __restrict__ fW2,
                                                 const float* __restrict__ fb2,
                                                 float* __restrict__ out) {
    __shared__ float y1[BATCH * 64];
    int tid = threadIdx.x;
    int b = tid >> 6, o = tid & 63;
    float acc = fb1[o];
#pragma unroll
    for (int j = 0; j < 128; ++j) acc += fW1[o * 128 + j] * pooled[b * 128 + j];
    y1[b * 64 + o] = fmaxf(acc, 0.0f);
    __syncthreads();
    if (tid < BATCH * 10) {
        int bb = tid / 10, o2 = tid % 10;
        float a2 = fb2[o2];
#pragma unroll
        for (int j = 0; j < 64; ++j) a2 += fW2[o2 * 64 + j] * y1[bb * 64 + j];
        out[bb * 10 + o2] = a2;
    }
}

extern "C" void kernel_launch(void* const* d_in, const int* in_sizes, int n_in,
                              void* d_out, int out_size, void* d_ws, size_t ws_size,
                              hipStream_t stream) {
    const float* x   = (const float*)d_in[0];
    const float* W0  = (const float*)d_in[1];
    const float* b0  = (const float*)d_in[2];
    const float* Wd  = (const float*)d_in[3];
    const float* bd  = (const float*)d_in[4];
    const float* W1  = (const float*)d_in[5];
    const float* b1  = (const float*)d_in[6];
    const float* Wf  = (const float*)d_in[7];
    const float* bf  = (const float*)d_in[8];
    const float* fW1 = (const float*)d_in[9];
    const float* fb1 = (const float*)d_in[10];
    const float* fW2 = (const float*)d_in[11];
    const float* fb2 = (const float*)d_in[12];
    float* out = (float*)d_out;

    const size_t HS = (size_t)BATCH * SEQ * CH;        // 4M floats = 16 MB
    float* bufA = (float*)d_ws;
    float* bufB = bufA + HS;
    unsigned short* wstream = (unsigned short*)(bufB + HS);   // 24 * 14336 shorts
    float* pooled = (float*)(wstream + (size_t)NB * 14336);

    k_prep<<<NB, 64, 0, stream>>>(Wd, bd, W1, b1, wstream, pooled);

    // stack 0: x -> B (h0 built in-LDS) ; stack 1: B -> A ; stack 2: A -> finale
    k_stack<<<256, 512, 0, stream>>>(bufA, bufB, x, W0, b0, Wf, bf, pooled, wstream, 0);
    k_stack<<<256, 512, 0, stream>>>(bufB, bufA, x, W0, b0, Wf, bf, pooled, wstream, 1);
    k_stack<<<256, 512, 0, stream>>>(bufA, bufA, x, W0, b0, Wf, bf, pooled, wstream, 2);

    k_final2<<<1, 1024, 0, stream>>>(pooled, fW1, fb1, fW2, fb2, out);
}